// Round 2
// baseline (884.930 us; speedup 1.0000x reference)
//
#include <hip/hip_runtime.h>
#include <hip/hip_bf16.h>
#include <math.h>

#define NB 16
#define ND 512
#define NN 2048
#define NKF 32       // feature width K
#define NNK 65536    // N*K

typedef short s8v __attribute__((ext_vector_type(8)));
typedef float f4v __attribute__((ext_vector_type(4)));
typedef unsigned short u16;
typedef unsigned int u32;
typedef u16 u16x8 __attribute__((ext_vector_type(8)));
typedef u32 u32x4 __attribute__((ext_vector_type(4)));

__device__ __forceinline__ u16 f2bf(float x) {
    u32 u = __builtin_bit_cast(u32, x);
    return (u16)((u + 0x7fffu + ((u >> 16) & 1u)) >> 16);
}
__device__ __forceinline__ float bf2f(u16 b) {
    u32 u = ((u32)b) << 16;
    return __builtin_bit_cast(float, u);
}

// ---------------- Kernel 1: QKV projection, 4-way d-split, bf16 partials --------
// grid (128, 3, 4), block 256 -> 1536 blocks (6/CU, 24 waves/CU).
// Thread owns 2 output columns, 16 batch accumulators. Ping-pong prefetch of
// 8-row W bundles keeps ~4KB/wave of loads in flight during FMA.
__global__ __launch_bounds__(256, 6) void proj_partial(
    const float* __restrict__ x,
    const float* __restrict__ WQ, const float* __restrict__ WK,
    const float* __restrict__ WV, u16* __restrict__ part)
{
    const int t = threadIdx.x;
    const int jb = blockIdx.x;       // 0..127
    const int mat = blockIdx.y;      // 0..2
    const int dz = blockIdx.z;       // 0..3
    const float* __restrict__ W = (mat == 0) ? WQ : (mat == 1) ? WK : WV;
    const int j = jb * 512 + t * 2;
    const int d0 = dz * 128;

    __shared__ float xs[128][16];   // xs[dd][b] = x[b][d0+dd]
    for (int i = t; i < 2048; i += 256) {
        int b = i & 15, dd = i >> 4;
        xs[dd][b] = x[b * ND + d0 + dd];
    }
    __syncthreads();

    float accx[16], accy[16];
    #pragma unroll
    for (int b = 0; b < 16; b++) { accx[b] = 0.f; accy[b] = 0.f; }

    const float* wp = W + (size_t)d0 * NNK + j;

    float2 wa[8], wb[8];
    #pragma unroll
    for (int u = 0; u < 8; u++) wa[u] = *(const float2*)(wp + (size_t)u * NNK);

    #pragma unroll 1
    for (int dd = 0; dd < 128; dd += 16) {
        // prefetch rows dd+8..dd+15 into wb BEFORE computing wa
        #pragma unroll
        for (int u = 0; u < 8; u++)
            wb[u] = *(const float2*)(wp + (size_t)(dd + 8 + u) * NNK);

        // compute rows dd..dd+7 from wa
        #pragma unroll
        for (int u = 0; u < 8; u++) {
            #pragma unroll
            for (int q = 0; q < 4; q++) {
                float4 xq = *(const float4*)&xs[dd + u][q * 4];
                accx[q * 4 + 0] = fmaf(xq.x, wa[u].x, accx[q * 4 + 0]);
                accy[q * 4 + 0] = fmaf(xq.x, wa[u].y, accy[q * 4 + 0]);
                accx[q * 4 + 1] = fmaf(xq.y, wa[u].x, accx[q * 4 + 1]);
                accy[q * 4 + 1] = fmaf(xq.y, wa[u].y, accy[q * 4 + 1]);
                accx[q * 4 + 2] = fmaf(xq.z, wa[u].x, accx[q * 4 + 2]);
                accy[q * 4 + 2] = fmaf(xq.z, wa[u].y, accy[q * 4 + 2]);
                accx[q * 4 + 3] = fmaf(xq.w, wa[u].x, accx[q * 4 + 3]);
                accy[q * 4 + 3] = fmaf(xq.w, wa[u].y, accy[q * 4 + 3]);
            }
        }

        // prefetch rows dd+16..dd+23 into wa BEFORE computing wb
        if (dd + 16 < 128) {
            #pragma unroll
            for (int u = 0; u < 8; u++)
                wa[u] = *(const float2*)(wp + (size_t)(dd + 16 + u) * NNK);
        }

        // compute rows dd+8..dd+15 from wb
        #pragma unroll
        for (int u = 0; u < 8; u++) {
            #pragma unroll
            for (int q = 0; q < 4; q++) {
                float4 xq = *(const float4*)&xs[dd + 8 + u][q * 4];
                accx[q * 4 + 0] = fmaf(xq.x, wb[u].x, accx[q * 4 + 0]);
                accy[q * 4 + 0] = fmaf(xq.x, wb[u].y, accy[q * 4 + 0]);
                accx[q * 4 + 1] = fmaf(xq.y, wb[u].x, accx[q * 4 + 1]);
                accy[q * 4 + 1] = fmaf(xq.y, wb[u].y, accy[q * 4 + 1]);
                accx[q * 4 + 2] = fmaf(xq.z, wb[u].x, accx[q * 4 + 2]);
                accy[q * 4 + 2] = fmaf(xq.z, wb[u].y, accy[q * 4 + 2]);
                accx[q * 4 + 3] = fmaf(xq.w, wb[u].x, accx[q * 4 + 3]);
                accy[q * 4 + 3] = fmaf(xq.w, wb[u].y, accy[q * 4 + 3]);
            }
        }
    }

    // store bf16 partials: part[(mat*4+dz)*16 + b][j..j+1]
    size_t base = ((size_t)(mat * 4 + dz) * 16) * NNK + j;
    #pragma unroll
    for (int b = 0; b < 16; b++) {
        u32 pv = (u32)f2bf(accx[b]) | ((u32)f2bf(accy[b]) << 16);
        *(u32*)(part + base + (size_t)b * NNK) = pv;
    }
}

// ---------------- Kernel 2: reduce 4 partials + bias, cast bf16; V transposed ----
// grid (32, 16, 3), block 256. K gets softmax scale folded in (base-2 domain).
__global__ __launch_bounds__(256) void reduce_cast(
    const u16* __restrict__ part,
    const float* __restrict__ bQ, const float* __restrict__ bK,
    const float* __restrict__ bV,
    u16* __restrict__ qb, u16* __restrict__ kb, u16* __restrict__ vT)
{
    const int t = threadIdx.x;
    const int jc = blockIdx.x;    // 0..31  (chunk of 2048 flat cols)
    const int b  = blockIdx.y;    // 0..15
    const int mat = blockIdx.z;   // 0..2
    const float* __restrict__ bias = (mat == 0) ? bQ : (mat == 1) ? bK : bV;
    const int j = jc * 2048 + t * 8;

    float4 b0 = *(const float4*)(bias + j);
    float4 b1 = *(const float4*)(bias + j + 4);
    float v[8] = {b0.x, b0.y, b0.z, b0.w, b1.x, b1.y, b1.z, b1.w};

    #pragma unroll
    for (int dz = 0; dz < 4; dz++) {
        size_t p = ((size_t)(mat * 4 + dz) * 16 + b) * NNK + j;
        u16x8 pp = *(const u16x8*)(part + p);
        #pragma unroll
        for (int i = 0; i < 8; i++) v[i] += bf2f(pp[i]);
    }

    const float scale = (mat == 1) ? 0.2550868230023389f : 1.0f; // log2(e)/sqrt(32)
    u16 h[8];
    #pragma unroll
    for (int i = 0; i < 8; i++) h[i] = f2bf(v[i] * scale);

    __shared__ u16 vt[32][72];  // padded transpose tile

    if (mat < 2) {
        u16* dst = ((mat == 0) ? qb : kb) + (size_t)b * NNK + j;
        u16x8 hv;
        #pragma unroll
        for (int i = 0; i < 8; i++) hv[i] = h[i];
        *(u16x8*)dst = hv;
    } else {
        const int n  = t >> 2;          // 0..63 local point
        const int k0 = (t & 3) * 8;     // feature start
        #pragma unroll
        for (int i = 0; i < 8; i++) vt[k0 + i][n] = h[i];
        __syncthreads();
        const int k  = t >> 3;          // 0..31
        const int c8 = t & 7;           // 0..7
        u16x8 ov;
        #pragma unroll
        for (int i = 0; i < 8; i++) ov[i] = vt[k][c8 * 8 + i];
        u16* dst = vT + (size_t)b * NNK + (size_t)k * NN + jc * 64 + c8 * 8;
        *(u16x8*)dst = ov;
    }
}

// ---------------- Kernel 3: fused flash attention + output/ori projection --------
// grid (32, 16), block 256 (4 waves x 16 q-rows). KVBLK=64, double-buffered LDS.
__global__ __launch_bounds__(256) void attn_kernel(
    const u16* __restrict__ qb, const u16* __restrict__ kb,
    const u16* __restrict__ vT,
    const float* __restrict__ Wout, const float* __restrict__ bout,
    const float* __restrict__ Wori, const float* __restrict__ bori,
    float* __restrict__ out)
{
    const int t = threadIdx.x;
    const int w = t >> 6;
    const int l = t & 63;
    const int g = l >> 4;
    const int n = l & 15;
    const int b = blockIdx.y;
    const int q0 = blockIdx.x * 64;

    __shared__ __align__(16) u16 Ks[2][2048];   // [64 kv][32 k] row-major
    __shared__ __align__(16) u16 Vs[2][2048];   // [32 dk][64 kv], col16 XOR-swizzled

    // Q fragment (B-operand of swapped QK^T): row q0+w*16+n, k = g*8..g*8+7
    const u16* qrow = qb + (size_t)b * NNK + (size_t)(q0 + w * 16 + n) * NKF + g * 8;
    const s8v qf = *(const s8v*)qrow;

    // staging addresses
    const int krow = t >> 2, kcol = (t & 3) * 8;
    const int vrow = t >> 3, vslot = t & 7;
    const int vcolL = (vslot ^ (vrow & 7)) * 8;   // pre-swizzled global column
    const u16* kgp = kb + (size_t)b * NNK + (size_t)krow * NKF + kcol;
    const u16* vgp = vT + (size_t)b * NNK + (size_t)vrow * NN + vcolL;

    s8v kreg, vreg;
    // tile 0 -> LDS buf0; tile 1 -> regs
    kreg = *(const s8v*)(kgp);                 vreg = *(const s8v*)(vgp);
    *(s8v*)(&Ks[0][t * 8]) = kreg;             *(s8v*)(&Vs[0][t * 8]) = vreg;
    kreg = *(const s8v*)(kgp + (size_t)2048);  vreg = *(const s8v*)(vgp + 64);
    __syncthreads();

    float m_run = -INFINITY, l_run = 0.f;
    f4v O0 = {0.f, 0.f, 0.f, 0.f}, O1 = {0.f, 0.f, 0.f, 0.f};
    const bool hi = (l >= 32);
    const int srcA = ((2 * g) & 3) * 16 + n;
    const int srcB = ((2 * g + 1) & 3) * 16 + n;

    for (int it = 0; it < 32; it++) {
        const int cur = it & 1;
        if (it + 1 < 32) {   // write tile it+1 from regs into the other buffer
            *(s8v*)(&Ks[cur ^ 1][t * 8]) = kreg;
            *(s8v*)(&Vs[cur ^ 1][t * 8]) = vreg;
        }
        if (it + 2 < 32) {   // prefetch tile it+2 into regs
            kreg = *(const s8v*)(kgp + (size_t)(it + 2) * 2048);
            vreg = *(const s8v*)(vgp + (size_t)(it + 2) * 64);
        }

        // ---- QK^T (swapped): S^T tiles, lane holds 16 scores for q-row n ----
        f4v S[4];
        #pragma unroll
        for (int tt = 0; tt < 4; tt++) {
            s8v ka = *(const s8v*)(&Ks[cur][(n + 16 * tt) * NKF + g * 8]);
            f4v z = {0.f, 0.f, 0.f, 0.f};
            S[tt] = __builtin_amdgcn_mfma_f32_16x16x32_bf16(ka, qf, z, 0, 0, 0);
        }

        // ---- online softmax in base-2 (scale folded into k) ----
        float pmax = -INFINITY;
        #pragma unroll
        for (int tt = 0; tt < 4; tt++)
            #pragma unroll
            for (int r = 0; r < 4; r++) pmax = fmaxf(pmax, S[tt][r]);
        pmax = fmaxf(pmax, __shfl_xor(pmax, 16));
        pmax = fmaxf(pmax, __shfl_xor(pmax, 32));
        const float m_new = fmaxf(m_run, pmax);
        const float corr = exp2f(m_run - m_new);

        float p[4][4];
        float tsum = 0.f;
        #pragma unroll
        for (int tt = 0; tt < 4; tt++)
            #pragma unroll
            for (int r = 0; r < 4; r++) {
                p[tt][r] = exp2f(S[tt][r] - m_new);
                tsum += p[tt][r];
            }
        tsum += __shfl_xor(tsum, 16);
        tsum += __shfl_xor(tsum, 32);
        l_run = l_run * corr + tsum;
        m_run = m_new;
        #pragma unroll
        for (int r = 0; r < 4; r++) { O0[r] *= corr; O1[r] *= corr; }

        // ---- pack P to bf16 pairs: pk[tt][j] covers kv = 16tt+4g+{2j,2j+1} ----
        u32 pk[4][2];
        #pragma unroll
        for (int tt = 0; tt < 4; tt++) {
            pk[tt][0] = (u32)f2bf(p[tt][0]) | ((u32)f2bf(p[tt][1]) << 16);
            pk[tt][1] = (u32)f2bf(p[tt][2]) | ((u32)f2bf(p[tt][3]) << 16);
        }

        // ---- shuffle to PV B-operand (P^T), then O^T += V^T * P^T ----
        #pragma unroll
        for (int kc = 0; kc < 2; kc++) {
            u32 lo0 = (u32)__shfl((int)pk[2 * kc][0], srcA);
            u32 hi0 = (u32)__shfl((int)pk[2 * kc + 1][0], srcA);
            u32 lo1 = (u32)__shfl((int)pk[2 * kc][1], srcA);
            u32 hi1 = (u32)__shfl((int)pk[2 * kc + 1][1], srcA);
            u32 lo2 = (u32)__shfl((int)pk[2 * kc][0], srcB);
            u32 hi2 = (u32)__shfl((int)pk[2 * kc + 1][0], srcB);
            u32 lo3 = (u32)__shfl((int)pk[2 * kc][1], srcB);
            u32 hi3 = (u32)__shfl((int)pk[2 * kc + 1][1], srcB);
            u32x4 fr;
            fr.x = hi ? hi0 : lo0;
            fr.y = hi ? hi1 : lo1;
            fr.z = hi ? hi2 : lo2;
            fr.w = hi ? hi3 : lo3;
            s8v pa = __builtin_bit_cast(s8v, fr);

            {   // dt = 0
                int row = n;
                int slot = (g + 4 * kc) ^ (row & 7);
                s8v va = *(const s8v*)(&Vs[cur][row * 64 + slot * 8]);
                O0 = __builtin_amdgcn_mfma_f32_16x16x32_bf16(va, pa, O0, 0, 0, 0);
            }
            {   // dt = 1
                int row = n + 16;
                int slot = (g + 4 * kc) ^ (row & 7);
                s8v va = *(const s8v*)(&Vs[cur][row * 64 + slot * 8]);
                O1 = __builtin_amdgcn_mfma_f32_16x16x32_bf16(va, pa, O1, 0, 0, 0);
            }
        }
        __syncthreads();
    }

    // ---- epilogue: out = O/l * Wout^T + q * Wori^T + bout + bori ----
    const float inv = 1.0f / l_run;
    float po[3] = {0.f, 0.f, 0.f};
    #pragma unroll
    for (int r = 0; r < 4; r++) {
        int dk0 = 4 * g + r;
        int dk1 = 16 + 4 * g + r;
        float o0 = O0[r] * inv;
        float o1 = O1[r] * inv;
        #pragma unroll
        for (int c = 0; c < 3; c++) {
            po[c] += o0 * Wout[c * NKF + dk0];
            po[c] += o1 * Wout[c * NKF + dk1];
        }
    }
    #pragma unroll
    for (int e = 0; e < 8; e++) {
        float qv = bf2f((u16)qf[e]);
        int k = 8 * g + e;
        #pragma unroll
        for (int c = 0; c < 3; c++) po[c] += qv * Wori[c * NKF + k];
    }
    #pragma unroll
    for (int c = 0; c < 3; c++) {
        po[c] += __shfl_xor(po[c], 16);
        po[c] += __shfl_xor(po[c], 32);
    }
    if (g == 0) {
        int row = q0 + w * 16 + n;
        size_t o = ((size_t)b * NN + row) * 3;
        #pragma unroll
        for (int c = 0; c < 3; c++) out[o + c] = po[c] + bout[c] + bori[c];
    }
}

// ---------------- launch ----------------
extern "C" void kernel_launch(void* const* d_in, const int* in_sizes, int n_in,
                              void* d_out, int out_size, void* d_ws, size_t ws_size,
                              hipStream_t stream) {
    const float* x    = (const float*)d_in[0];
    const float* WQ   = (const float*)d_in[1];
    const float* bQ   = (const float*)d_in[2];
    const float* WK   = (const float*)d_in[3];
    const float* bK   = (const float*)d_in[4];
    const float* WV   = (const float*)d_in[5];
    const float* bV   = (const float*)d_in[6];
    const float* Wout = (const float*)d_in[7];
    const float* bout = (const float*)d_in[8];
    const float* Wori = (const float*)d_in[9];
    const float* bori = (const float*)d_in[10];
    float* out = (float*)d_out;

    char* ws = (char*)d_ws;
    u16* part = (u16*)ws;                              // 3*4*16*65536*2 = 25165824 B
    u16* qb = (u16*)(ws + 25165824);                   // 2 MB
    u16* kb = (u16*)(ws + 25165824 + 2097152);         // 2 MB
    u16* vT = (u16*)(ws + 25165824 + 2 * 2097152);     // 2 MB

    proj_partial<<<dim3(128, 3, 4), 256, 0, stream>>>(x, WQ, WK, WV, part);
    reduce_cast<<<dim3(32, 16, 3), 256, 0, stream>>>(part, bQ, bK, bV, qb, kb, vT);
    attn_kernel<<<dim3(32, 16), 256, 0, stream>>>(qb, kb, vT, Wout, bout, Wori, bori, out);
}

// Round 3
// 135.795 us; speedup vs baseline: 6.5167x; 6.5167x over previous
//
#include <hip/hip_runtime.h>
#include <hip/hip_bf16.h>
#include <math.h>

#define NB 16
#define ND 512
#define NN 2048
#define NKF 32       // feature width K
#define NNK 65536    // N*K

typedef short s8v __attribute__((ext_vector_type(8)));
typedef float f4v __attribute__((ext_vector_type(4)));
typedef unsigned short u16;
typedef unsigned int u32;
typedef u16 u16x8 __attribute__((ext_vector_type(8)));
typedef u32 u32x4 __attribute__((ext_vector_type(4)));

__device__ __forceinline__ u16 f2bf(float x) {
    u32 u = __builtin_bit_cast(u32, x);
    return (u16)((u + 0x7fffu + ((u >> 16) & 1u)) >> 16);
}
__device__ __forceinline__ float bf2f(u16 b) {
    u32 u = ((u32)b) << 16;
    return __builtin_bit_cast(float, u);
}

// ---------------- Kernel 1: QKV projection, 4-way d-split, bf16 partials --------
// grid (128, 3, 4), block 256 -> 1536 blocks (6/CU). Thread owns 2 output
// columns, 16 batch accumulators. x is read via wave-uniform scalar loads
// (s_load, SMEM pipe) -- no LDS. Ping-pong register dbuf keeps 8 W-rows in
// flight during FMA; sched_barrier pins the prefetch above the compute so the
// compiler can't sink it (R1 failure). NO min-waves launch bound (R2 spilled).
__global__ __launch_bounds__(256) void proj_partial(
    const float* __restrict__ x,
    const float* __restrict__ WQ, const float* __restrict__ WK,
    const float* __restrict__ WV, u16* __restrict__ part)
{
    const int t = threadIdx.x;
    const int jb = blockIdx.x;       // 0..127
    const int mat = blockIdx.y;      // 0..2
    const int dz = blockIdx.z;       // 0..3
    const float* __restrict__ W = (mat == 0) ? WQ : (mat == 1) ? WK : WV;
    const int j = jb * 512 + t * 2;
    const int d0 = dz * 128;

    float accx[16], accy[16];
    #pragma unroll
    for (int b = 0; b < 16; b++) { accx[b] = 0.f; accy[b] = 0.f; }

    const float* wp = W + (size_t)d0 * NNK + j;
    const float* xp = x + d0;        // xp[b*ND + dd] is wave-uniform -> s_load

    float2 wa[8], wb[8];
    #pragma unroll
    for (int u = 0; u < 8; u++) wa[u] = *(const float2*)(wp + (size_t)u * NNK);

    #pragma unroll 1
    for (int dd = 0; dd < 128; dd += 16) {
        // prefetch rows dd+8..dd+15 into wb, pinned above the wa compute
        #pragma unroll
        for (int u = 0; u < 8; u++)
            wb[u] = *(const float2*)(wp + (size_t)(dd + 8 + u) * NNK);
        __builtin_amdgcn_sched_barrier(0);

        // compute rows dd..dd+7 from wa (x via uniform scalar loads)
        #pragma unroll
        for (int u = 0; u < 8; u++) {
            const float* xr = xp + dd + u;
            #pragma unroll
            for (int b = 0; b < 16; b++) {
                float xv = xr[b * ND];
                accx[b] = fmaf(xv, wa[u].x, accx[b]);
                accy[b] = fmaf(xv, wa[u].y, accy[b]);
            }
        }

        // prefetch rows dd+16..dd+23 into wa, pinned above the wb compute
        if (dd + 16 < 128) {
            #pragma unroll
            for (int u = 0; u < 8; u++)
                wa[u] = *(const float2*)(wp + (size_t)(dd + 16 + u) * NNK);
        }
        __builtin_amdgcn_sched_barrier(0);

        // compute rows dd+8..dd+15 from wb
        #pragma unroll
        for (int u = 0; u < 8; u++) {
            const float* xr = xp + dd + 8 + u;
            #pragma unroll
            for (int b = 0; b < 16; b++) {
                float xv = xr[b * ND];
                accx[b] = fmaf(xv, wb[u].x, accx[b]);
                accy[b] = fmaf(xv, wb[u].y, accy[b]);
            }
        }
    }

    // store bf16 partials: part[(mat*4+dz)*16 + b][j..j+1]
    size_t base = ((size_t)(mat * 4 + dz) * 16) * NNK + j;
    #pragma unroll
    for (int b = 0; b < 16; b++) {
        u32 pv = (u32)f2bf(accx[b]) | ((u32)f2bf(accy[b]) << 16);
        *(u32*)(part + base + (size_t)b * NNK) = pv;
    }
}

// ---------------- Kernel 2: reduce 4 partials + bias, cast bf16; V transposed ----
// grid (32, 16, 3), block 256. K gets softmax scale folded in (base-2 domain).
__global__ __launch_bounds__(256) void reduce_cast(
    const u16* __restrict__ part,
    const float* __restrict__ bQ, const float* __restrict__ bK,
    const float* __restrict__ bV,
    u16* __restrict__ qb, u16* __restrict__ kb, u16* __restrict__ vT)
{
    const int t = threadIdx.x;
    const int jc = blockIdx.x;    // 0..31  (chunk of 2048 flat cols)
    const int b  = blockIdx.y;    // 0..15
    const int mat = blockIdx.z;   // 0..2
    const float* __restrict__ bias = (mat == 0) ? bQ : (mat == 1) ? bK : bV;
    const int j = jc * 2048 + t * 8;

    float4 b0 = *(const float4*)(bias + j);
    float4 b1 = *(const float4*)(bias + j + 4);
    float v[8] = {b0.x, b0.y, b0.z, b0.w, b1.x, b1.y, b1.z, b1.w};

    #pragma unroll
    for (int dz = 0; dz < 4; dz++) {
        size_t p = ((size_t)(mat * 4 + dz) * 16 + b) * NNK + j;
        u16x8 pp = *(const u16x8*)(part + p);
        #pragma unroll
        for (int i = 0; i < 8; i++) v[i] += bf2f(pp[i]);
    }

    const float scale = (mat == 1) ? 0.2550868230023389f : 1.0f; // log2(e)/sqrt(32)
    u16 h[8];
    #pragma unroll
    for (int i = 0; i < 8; i++) h[i] = f2bf(v[i] * scale);

    __shared__ u16 vt[32][72];  // padded transpose tile

    if (mat < 2) {
        u16* dst = ((mat == 0) ? qb : kb) + (size_t)b * NNK + j;
        u16x8 hv;
        #pragma unroll
        for (int i = 0; i < 8; i++) hv[i] = h[i];
        *(u16x8*)dst = hv;
    } else {
        const int n  = t >> 2;          // 0..63 local point
        const int k0 = (t & 3) * 8;     // feature start
        #pragma unroll
        for (int i = 0; i < 8; i++) vt[k0 + i][n] = h[i];
        __syncthreads();
        const int k  = t >> 3;          // 0..31
        const int c8 = t & 7;           // 0..7
        u16x8 ov;
        #pragma unroll
        for (int i = 0; i < 8; i++) ov[i] = vt[k][c8 * 8 + i];
        u16* dst = vT + (size_t)b * NNK + (size_t)k * NN + jc * 64 + c8 * 8;
        *(u16x8*)dst = ov;
    }
}

// ---------------- Kernel 3: fused flash attention + output/ori projection --------
// grid (32, 16), block 256 (4 waves x 16 q-rows). KVBLK=64, double-buffered LDS.
__global__ __launch_bounds__(256) void attn_kernel(
    const u16* __restrict__ qb, const u16* __restrict__ kb,
    const u16* __restrict__ vT,
    const float* __restrict__ Wout, const float* __restrict__ bout,
    const float* __restrict__ Wori, const float* __restrict__ bori,
    float* __restrict__ out)
{
    const int t = threadIdx.x;
    const int w = t >> 6;
    const int l = t & 63;
    const int g = l >> 4;
    const int n = l & 15;
    const int b = blockIdx.y;
    const int q0 = blockIdx.x * 64;

    __shared__ __align__(16) u16 Ks[2][2048];   // [64 kv][32 k] row-major
    __shared__ __align__(16) u16 Vs[2][2048];   // [32 dk][64 kv], col16 XOR-swizzled

    // Q fragment (B-operand of swapped QK^T): row q0+w*16+n, k = g*8..g*8+7
    const u16* qrow = qb + (size_t)b * NNK + (size_t)(q0 + w * 16 + n) * NKF + g * 8;
    const s8v qf = *(const s8v*)qrow;

    // staging addresses
    const int krow = t >> 2, kcol = (t & 3) * 8;
    const int vrow = t >> 3, vslot = t & 7;
    const int vcolL = (vslot ^ (vrow & 7)) * 8;   // pre-swizzled global column
    const u16* kgp = kb + (size_t)b * NNK + (size_t)krow * NKF + kcol;
    const u16* vgp = vT + (size_t)b * NNK + (size_t)vrow * NN + vcolL;

    s8v kreg, vreg;
    // tile 0 -> LDS buf0; tile 1 -> regs
    kreg = *(const s8v*)(kgp);                 vreg = *(const s8v*)(vgp);
    *(s8v*)(&Ks[0][t * 8]) = kreg;             *(s8v*)(&Vs[0][t * 8]) = vreg;
    kreg = *(const s8v*)(kgp + (size_t)2048);  vreg = *(const s8v*)(vgp + 64);
    __syncthreads();

    float m_run = -INFINITY, l_run = 0.f;
    f4v O0 = {0.f, 0.f, 0.f, 0.f}, O1 = {0.f, 0.f, 0.f, 0.f};
    const bool hi = (l >= 32);
    const int srcA = ((2 * g) & 3) * 16 + n;
    const int srcB = ((2 * g + 1) & 3) * 16 + n;

    for (int it = 0; it < 32; it++) {
        const int cur = it & 1;
        if (it + 1 < 32) {   // write tile it+1 from regs into the other buffer
            *(s8v*)(&Ks[cur ^ 1][t * 8]) = kreg;
            *(s8v*)(&Vs[cur ^ 1][t * 8]) = vreg;
        }
        if (it + 2 < 32) {   // prefetch tile it+2 into regs
            kreg = *(const s8v*)(kgp + (size_t)(it + 2) * 2048);
            vreg = *(const s8v*)(vgp + (size_t)(it + 2) * 64);
        }

        // ---- QK^T (swapped): S^T tiles, lane holds 16 scores for q-row n ----
        f4v S[4];
        #pragma unroll
        for (int tt = 0; tt < 4; tt++) {
            s8v ka = *(const s8v*)(&Ks[cur][(n + 16 * tt) * NKF + g * 8]);
            f4v z = {0.f, 0.f, 0.f, 0.f};
            S[tt] = __builtin_amdgcn_mfma_f32_16x16x32_bf16(ka, qf, z, 0, 0, 0);
        }

        // ---- online softmax in base-2 (scale folded into k) ----
        float pmax = -INFINITY;
        #pragma unroll
        for (int tt = 0; tt < 4; tt++)
            #pragma unroll
            for (int r = 0; r < 4; r++) pmax = fmaxf(pmax, S[tt][r]);
        pmax = fmaxf(pmax, __shfl_xor(pmax, 16));
        pmax = fmaxf(pmax, __shfl_xor(pmax, 32));
        const float m_new = fmaxf(m_run, pmax);
        const float corr = exp2f(m_run - m_new);

        float p[4][4];
        float tsum = 0.f;
        #pragma unroll
        for (int tt = 0; tt < 4; tt++)
            #pragma unroll
            for (int r = 0; r < 4; r++) {
                p[tt][r] = exp2f(S[tt][r] - m_new);
                tsum += p[tt][r];
            }
        tsum += __shfl_xor(tsum, 16);
        tsum += __shfl_xor(tsum, 32);
        l_run = l_run * corr + tsum;
        m_run = m_new;
        #pragma unroll
        for (int r = 0; r < 4; r++) { O0[r] *= corr; O1[r] *= corr; }

        // ---- pack P to bf16 pairs: pk[tt][j] covers kv = 16tt+4g+{2j,2j+1} ----
        u32 pk[4][2];
        #pragma unroll
        for (int tt = 0; tt < 4; tt++) {
            pk[tt][0] = (u32)f2bf(p[tt][0]) | ((u32)f2bf(p[tt][1]) << 16);
            pk[tt][1] = (u32)f2bf(p[tt][2]) | ((u32)f2bf(p[tt][3]) << 16);
        }

        // ---- shuffle to PV B-operand (P^T), then O^T += V^T * P^T ----
        #pragma unroll
        for (int kc = 0; kc < 2; kc++) {
            u32 lo0 = (u32)__shfl((int)pk[2 * kc][0], srcA);
            u32 hi0 = (u32)__shfl((int)pk[2 * kc + 1][0], srcA);
            u32 lo1 = (u32)__shfl((int)pk[2 * kc][1], srcA);
            u32 hi1 = (u32)__shfl((int)pk[2 * kc + 1][1], srcA);
            u32 lo2 = (u32)__shfl((int)pk[2 * kc][0], srcB);
            u32 hi2 = (u32)__shfl((int)pk[2 * kc + 1][0], srcB);
            u32 lo3 = (u32)__shfl((int)pk[2 * kc][1], srcB);
            u32 hi3 = (u32)__shfl((int)pk[2 * kc + 1][1], srcB);
            u32x4 fr;
            fr.x = hi ? hi0 : lo0;
            fr.y = hi ? hi1 : lo1;
            fr.z = hi ? hi2 : lo2;
            fr.w = hi ? hi3 : lo3;
            s8v pa = __builtin_bit_cast(s8v, fr);

            {   // dt = 0
                int row = n;
                int slot = (g + 4 * kc) ^ (row & 7);
                s8v va = *(const s8v*)(&Vs[cur][row * 64 + slot * 8]);
                O0 = __builtin_amdgcn_mfma_f32_16x16x32_bf16(va, pa, O0, 0, 0, 0);
            }
            {   // dt = 1
                int row = n + 16;
                int slot = (g + 4 * kc) ^ (row & 7);
                s8v va = *(const s8v*)(&Vs[cur][row * 64 + slot * 8]);
                O1 = __builtin_amdgcn_mfma_f32_16x16x32_bf16(va, pa, O1, 0, 0, 0);
            }
        }
        __syncthreads();
    }

    // ---- epilogue: out = O/l * Wout^T + q * Wori^T + bout + bori ----
    const float inv = 1.0f / l_run;
    float po[3] = {0.f, 0.f, 0.f};
    #pragma unroll
    for (int r = 0; r < 4; r++) {
        int dk0 = 4 * g + r;
        int dk1 = 16 + 4 * g + r;
        float o0 = O0[r] * inv;
        float o1 = O1[r] * inv;
        #pragma unroll
        for (int c = 0; c < 3; c++) {
            po[c] += o0 * Wout[c * NKF + dk0];
            po[c] += o1 * Wout[c * NKF + dk1];
        }
    }
    #pragma unroll
    for (int e = 0; e < 8; e++) {
        float qv = bf2f((u16)qf[e]);
        int k = 8 * g + e;
        #pragma unroll
        for (int c = 0; c < 3; c++) po[c] += qv * Wori[c * NKF + k];
    }
    #pragma unroll
    for (int c = 0; c < 3; c++) {
        po[c] += __shfl_xor(po[c], 16);
        po[c] += __shfl_xor(po[c], 32);
    }
    if (g == 0) {
        int row = q0 + w * 16 + n;
        size_t o = ((size_t)b * NN + row) * 3;
        #pragma unroll
        for (int c = 0; c < 3; c++) out[o + c] = po[c] + bout[c] + bori[c];
    }
}

// ---------------- launch ----------------
extern "C" void kernel_launch(void* const* d_in, const int* in_sizes, int n_in,
                              void* d_out, int out_size, void* d_ws, size_t ws_size,
                              hipStream_t stream) {
    const float* x    = (const float*)d_in[0];
    const float* WQ   = (const float*)d_in[1];
    const float* bQ   = (const float*)d_in[2];
    const float* WK   = (const float*)d_in[3];
    const float* bK   = (const float*)d_in[4];
    const float* WV   = (const float*)d_in[5];
    const float* bV   = (const float*)d_in[6];
    const float* Wout = (const float*)d_in[7];
    const float* bout = (const float*)d_in[8];
    const float* Wori = (const float*)d_in[9];
    const float* bori = (const float*)d_in[10];
    float* out = (float*)d_out;

    char* ws = (char*)d_ws;
    u16* part = (u16*)ws;                              // 3*4*16*65536*2 = 25165824 B
    u16* qb = (u16*)(ws + 25165824);                   // 2 MB
    u16* kb = (u16*)(ws + 25165824 + 2097152);         // 2 MB
    u16* vT = (u16*)(ws + 25165824 + 2 * 2097152);     // 2 MB

    proj_partial<<<dim3(128, 3, 4), 256, 0, stream>>>(x, WQ, WK, WV, part);
    reduce_cast<<<dim3(32, 16, 3), 256, 0, stream>>>(part, bQ, bK, bV, qb, kb, vT);
    attn_kernel<<<dim3(32, 16), 256, 0, stream>>>(qb, kb, vT, Wout, bout, Wori, bori, out);
}

// Round 4
// 132.101 us; speedup vs baseline: 6.6989x; 1.0280x over previous
//
#include <hip/hip_runtime.h>
#include <hip/hip_bf16.h>
#include <math.h>

#define NB 16
#define ND 512
#define NN 2048
#define NKF 32       // feature width K
#define NNK 65536    // N*K

typedef short s8v __attribute__((ext_vector_type(8)));
typedef float f4v __attribute__((ext_vector_type(4)));
typedef unsigned short u16;
typedef unsigned int u32;
typedef u16 u16x8 __attribute__((ext_vector_type(8)));
typedef u32 u32x4 __attribute__((ext_vector_type(4)));

__device__ __forceinline__ u16 f2bf(float x) {
    u32 u = __builtin_bit_cast(u32, x);
    return (u16)((u + 0x7fffu + ((u >> 16) & 1u)) >> 16);
}
__device__ __forceinline__ float bf2f(u16 b) {
    u32 u = ((u32)b) << 16;
    return __builtin_bit_cast(float, u);
}

// ---------------- Kernel 1: QKV projection, float4 panels, dense streams --------
// grid (64, 3, 4), block 256 -> 768 blocks = exactly 3/CU, ALL co-resident.
// Panel width 1024 floats: the 64 jb-blocks of one (mat,dz) combo tile a full
// contiguous 256KB W-row and sweep rows together -> 12 dense sequential DRAM
// streams (R1/R3 had 1536 scattered 512B streams -> 1.7 TB/s wall).
// Thread: 4 cols (float4) x 16 batches = 64 fp32 acc. 8-row ping-pong keeps
// 8KB/wave in flight with ~1024-cycle slack. x via wave-uniform s_load.
__global__ __launch_bounds__(256) void proj_partial(
    const float* __restrict__ x,
    const float* __restrict__ WQ, const float* __restrict__ WK,
    const float* __restrict__ WV, u16* __restrict__ part)
{
    const int t = threadIdx.x;
    const int jb = blockIdx.x;       // 0..63
    const int mat = blockIdx.y;      // 0..2
    const int dz = blockIdx.z;       // 0..3
    const float* __restrict__ W = (mat == 0) ? WQ : (mat == 1) ? WK : WV;
    const int j = jb * 1024 + t * 4;
    const int d0 = dz * 128;

    float4 acc[16];
    #pragma unroll
    for (int b = 0; b < 16; b++) acc[b] = make_float4(0.f, 0.f, 0.f, 0.f);

    const float* wp = W + (size_t)d0 * NNK + j;
    const float* xp = x + d0;        // xp[b*ND + dd] is wave-uniform -> s_load

    float4 wa[8], wb[8];
    #pragma unroll
    for (int u = 0; u < 8; u++) wa[u] = *(const float4*)(wp + (size_t)u * NNK);

    #pragma unroll 1
    for (int dd = 0; dd < 128; dd += 16) {
        // prefetch rows dd+8..dd+15 into wb, pinned above the wa compute
        #pragma unroll
        for (int u = 0; u < 8; u++)
            wb[u] = *(const float4*)(wp + (size_t)(dd + 8 + u) * NNK);
        __builtin_amdgcn_sched_barrier(0);

        // compute rows dd..dd+7 from wa (x via uniform scalar loads)
        #pragma unroll
        for (int u = 0; u < 8; u++) {
            const float* xr = xp + dd + u;
            #pragma unroll
            for (int b = 0; b < 16; b++) {
                float xv = xr[b * ND];
                acc[b].x = fmaf(xv, wa[u].x, acc[b].x);
                acc[b].y = fmaf(xv, wa[u].y, acc[b].y);
                acc[b].z = fmaf(xv, wa[u].z, acc[b].z);
                acc[b].w = fmaf(xv, wa[u].w, acc[b].w);
            }
        }

        // prefetch rows dd+16..dd+23 into wa, pinned above the wb compute
        if (dd + 16 < 128) {
            #pragma unroll
            for (int u = 0; u < 8; u++)
                wa[u] = *(const float4*)(wp + (size_t)(dd + 16 + u) * NNK);
        }
        __builtin_amdgcn_sched_barrier(0);

        // compute rows dd+8..dd+15 from wb
        #pragma unroll
        for (int u = 0; u < 8; u++) {
            const float* xr = xp + dd + 8 + u;
            #pragma unroll
            for (int b = 0; b < 16; b++) {
                float xv = xr[b * ND];
                acc[b].x = fmaf(xv, wb[u].x, acc[b].x);
                acc[b].y = fmaf(xv, wb[u].y, acc[b].y);
                acc[b].z = fmaf(xv, wb[u].z, acc[b].z);
                acc[b].w = fmaf(xv, wb[u].w, acc[b].w);
            }
        }
    }

    // store bf16 partials: part[(mat*4+dz)*16 + b][j..j+3]
    size_t base = ((size_t)(mat * 4 + dz) * 16) * NNK + j;
    #pragma unroll
    for (int b = 0; b < 16; b++) {
        u32 lo = (u32)f2bf(acc[b].x) | ((u32)f2bf(acc[b].y) << 16);
        u32 hi = (u32)f2bf(acc[b].z) | ((u32)f2bf(acc[b].w) << 16);
        *(uint2*)(part + base + (size_t)b * NNK) = make_uint2(lo, hi);
    }
}

// ---------------- Kernel 2: reduce 4 partials + bias, cast bf16; V transposed ----
// grid (32, 16, 3), block 256. K gets softmax scale folded in (base-2 domain).
__global__ __launch_bounds__(256) void reduce_cast(
    const u16* __restrict__ part,
    const float* __restrict__ bQ, const float* __restrict__ bK,
    const float* __restrict__ bV,
    u16* __restrict__ qb, u16* __restrict__ kb, u16* __restrict__ vT)
{
    const int t = threadIdx.x;
    const int jc = blockIdx.x;    // 0..31  (chunk of 2048 flat cols)
    const int b  = blockIdx.y;    // 0..15
    const int mat = blockIdx.z;   // 0..2
    const float* __restrict__ bias = (mat == 0) ? bQ : (mat == 1) ? bK : bV;
    const int j = jc * 2048 + t * 8;

    float4 b0 = *(const float4*)(bias + j);
    float4 b1 = *(const float4*)(bias + j + 4);
    float v[8] = {b0.x, b0.y, b0.z, b0.w, b1.x, b1.y, b1.z, b1.w};

    #pragma unroll
    for (int dz = 0; dz < 4; dz++) {
        size_t p = ((size_t)(mat * 4 + dz) * 16 + b) * NNK + j;
        u16x8 pp = *(const u16x8*)(part + p);
        #pragma unroll
        for (int i = 0; i < 8; i++) v[i] += bf2f(pp[i]);
    }

    const float scale = (mat == 1) ? 0.2550868230023389f : 1.0f; // log2(e)/sqrt(32)
    u16 h[8];
    #pragma unroll
    for (int i = 0; i < 8; i++) h[i] = f2bf(v[i] * scale);

    __shared__ u16 vt[32][72];  // padded transpose tile

    if (mat < 2) {
        u16* dst = ((mat == 0) ? qb : kb) + (size_t)b * NNK + j;
        u16x8 hv;
        #pragma unroll
        for (int i = 0; i < 8; i++) hv[i] = h[i];
        *(u16x8*)dst = hv;
    } else {
        const int n  = t >> 2;          // 0..63 local point
        const int k0 = (t & 3) * 8;     // feature start
        #pragma unroll
        for (int i = 0; i < 8; i++) vt[k0 + i][n] = h[i];
        __syncthreads();
        const int k  = t >> 3;          // 0..31
        const int c8 = t & 7;           // 0..7
        u16x8 ov;
        #pragma unroll
        for (int i = 0; i < 8; i++) ov[i] = vt[k][c8 * 8 + i];
        u16* dst = vT + (size_t)b * NNK + (size_t)k * NN + jc * 64 + c8 * 8;
        *(u16x8*)dst = ov;
    }
}

// ---------------- Kernel 3: fused flash attention + output/ori projection --------
// grid (32, 16), block 256 (4 waves x 16 q-rows). KVBLK=64, double-buffered LDS.
__global__ __launch_bounds__(256) void attn_kernel(
    const u16* __restrict__ qb, const u16* __restrict__ kb,
    const u16* __restrict__ vT,
    const float* __restrict__ Wout, const float* __restrict__ bout,
    const float* __restrict__ Wori, const float* __restrict__ bori,
    float* __restrict__ out)
{
    const int t = threadIdx.x;
    const int w = t >> 6;
    const int l = t & 63;
    const int g = l >> 4;
    const int n = l & 15;
    const int b = blockIdx.y;
    const int q0 = blockIdx.x * 64;

    __shared__ __align__(16) u16 Ks[2][2048];   // [64 kv][32 k] row-major
    __shared__ __align__(16) u16 Vs[2][2048];   // [32 dk][64 kv], col16 XOR-swizzled

    // Q fragment (B-operand of swapped QK^T): row q0+w*16+n, k = g*8..g*8+7
    const u16* qrow = qb + (size_t)b * NNK + (size_t)(q0 + w * 16 + n) * NKF + g * 8;
    const s8v qf = *(const s8v*)qrow;

    // staging addresses
    const int krow = t >> 2, kcol = (t & 3) * 8;
    const int vrow = t >> 3, vslot = t & 7;
    const int vcolL = (vslot ^ (vrow & 7)) * 8;   // pre-swizzled global column
    const u16* kgp = kb + (size_t)b * NNK + (size_t)krow * NKF + kcol;
    const u16* vgp = vT + (size_t)b * NNK + (size_t)vrow * NN + vcolL;

    s8v kreg, vreg;
    // tile 0 -> LDS buf0; tile 1 -> regs
    kreg = *(const s8v*)(kgp);                 vreg = *(const s8v*)(vgp);
    *(s8v*)(&Ks[0][t * 8]) = kreg;             *(s8v*)(&Vs[0][t * 8]) = vreg;
    kreg = *(const s8v*)(kgp + (size_t)2048);  vreg = *(const s8v*)(vgp + 64);
    __syncthreads();

    float m_run = -INFINITY, l_run = 0.f;
    f4v O0 = {0.f, 0.f, 0.f, 0.f}, O1 = {0.f, 0.f, 0.f, 0.f};
    const bool hi = (l >= 32);
    const int srcA = ((2 * g) & 3) * 16 + n;
    const int srcB = ((2 * g + 1) & 3) * 16 + n;

    for (int it = 0; it < 32; it++) {
        const int cur = it & 1;
        if (it + 1 < 32) {   // write tile it+1 from regs into the other buffer
            *(s8v*)(&Ks[cur ^ 1][t * 8]) = kreg;
            *(s8v*)(&Vs[cur ^ 1][t * 8]) = vreg;
        }
        if (it + 2 < 32) {   // prefetch tile it+2 into regs
            kreg = *(const s8v*)(kgp + (size_t)(it + 2) * 2048);
            vreg = *(const s8v*)(vgp + (size_t)(it + 2) * 64);
        }

        // ---- QK^T (swapped): S^T tiles, lane holds 16 scores for q-row n ----
        f4v S[4];
        #pragma unroll
        for (int tt = 0; tt < 4; tt++) {
            s8v ka = *(const s8v*)(&Ks[cur][(n + 16 * tt) * NKF + g * 8]);
            f4v z = {0.f, 0.f, 0.f, 0.f};
            S[tt] = __builtin_amdgcn_mfma_f32_16x16x32_bf16(ka, qf, z, 0, 0, 0);
        }

        // ---- online softmax in base-2 (scale folded into k) ----
        float pmax = -INFINITY;
        #pragma unroll
        for (int tt = 0; tt < 4; tt++)
            #pragma unroll
            for (int r = 0; r < 4; r++) pmax = fmaxf(pmax, S[tt][r]);
        pmax = fmaxf(pmax, __shfl_xor(pmax, 16));
        pmax = fmaxf(pmax, __shfl_xor(pmax, 32));
        const float m_new = fmaxf(m_run, pmax);
        const float corr = exp2f(m_run - m_new);

        float p[4][4];
        float tsum = 0.f;
        #pragma unroll
        for (int tt = 0; tt < 4; tt++)
            #pragma unroll
            for (int r = 0; r < 4; r++) {
                p[tt][r] = exp2f(S[tt][r] - m_new);
                tsum += p[tt][r];
            }
        tsum += __shfl_xor(tsum, 16);
        tsum += __shfl_xor(tsum, 32);
        l_run = l_run * corr + tsum;
        m_run = m_new;
        #pragma unroll
        for (int r = 0; r < 4; r++) { O0[r] *= corr; O1[r] *= corr; }

        // ---- pack P to bf16 pairs: pk[tt][j] covers kv = 16tt+4g+{2j,2j+1} ----
        u32 pk[4][2];
        #pragma unroll
        for (int tt = 0; tt < 4; tt++) {
            pk[tt][0] = (u32)f2bf(p[tt][0]) | ((u32)f2bf(p[tt][1]) << 16);
            pk[tt][1] = (u32)f2bf(p[tt][2]) | ((u32)f2bf(p[tt][3]) << 16);
        }

        // ---- shuffle to PV B-operand (P^T), then O^T += V^T * P^T ----
        #pragma unroll
        for (int kc = 0; kc < 2; kc++) {
            u32 lo0 = (u32)__shfl((int)pk[2 * kc][0], srcA);
            u32 hi0 = (u32)__shfl((int)pk[2 * kc + 1][0], srcA);
            u32 lo1 = (u32)__shfl((int)pk[2 * kc][1], srcA);
            u32 hi1 = (u32)__shfl((int)pk[2 * kc + 1][1], srcA);
            u32 lo2 = (u32)__shfl((int)pk[2 * kc][0], srcB);
            u32 hi2 = (u32)__shfl((int)pk[2 * kc + 1][0], srcB);
            u32 lo3 = (u32)__shfl((int)pk[2 * kc][1], srcB);
            u32 hi3 = (u32)__shfl((int)pk[2 * kc + 1][1], srcB);
            u32x4 fr;
            fr.x = hi ? hi0 : lo0;
            fr.y = hi ? hi1 : lo1;
            fr.z = hi ? hi2 : lo2;
            fr.w = hi ? hi3 : lo3;
            s8v pa = __builtin_bit_cast(s8v, fr);

            {   // dt = 0
                int row = n;
                int slot = (g + 4 * kc) ^ (row & 7);
                s8v va = *(const s8v*)(&Vs[cur][row * 64 + slot * 8]);
                O0 = __builtin_amdgcn_mfma_f32_16x16x32_bf16(va, pa, O0, 0, 0, 0);
            }
            {   // dt = 1
                int row = n + 16;
                int slot = (g + 4 * kc) ^ (row & 7);
                s8v va = *(const s8v*)(&Vs[cur][row * 64 + slot * 8]);
                O1 = __builtin_amdgcn_mfma_f32_16x16x32_bf16(va, pa, O1, 0, 0, 0);
            }
        }
        __syncthreads();
    }

    // ---- epilogue: out = O/l * Wout^T + q * Wori^T + bout + bori ----
    const float inv = 1.0f / l_run;
    float po[3] = {0.f, 0.f, 0.f};
    #pragma unroll
    for (int r = 0; r < 4; r++) {
        int dk0 = 4 * g + r;
        int dk1 = 16 + 4 * g + r;
        float o0 = O0[r] * inv;
        float o1 = O1[r] * inv;
        #pragma unroll
        for (int c = 0; c < 3; c++) {
            po[c] += o0 * Wout[c * NKF + dk0];
            po[c] += o1 * Wout[c * NKF + dk1];
        }
    }
    #pragma unroll
    for (int e = 0; e < 8; e++) {
        float qv = bf2f((u16)qf[e]);
        int k = 8 * g + e;
        #pragma unroll
        for (int c = 0; c < 3; c++) po[c] += qv * Wori[c * NKF + k];
    }
    #pragma unroll
    for (int c = 0; c < 3; c++) {
        po[c] += __shfl_xor(po[c], 16);
        po[c] += __shfl_xor(po[c], 32);
    }
    if (g == 0) {
        int row = q0 + w * 16 + n;
        size_t o = ((size_t)b * NN + row) * 3;
        #pragma unroll
        for (int c = 0; c < 3; c++) out[o + c] = po[c] + bout[c] + bori[c];
    }
}

// ---------------- launch ----------------
extern "C" void kernel_launch(void* const* d_in, const int* in_sizes, int n_in,
                              void* d_out, int out_size, void* d_ws, size_t ws_size,
                              hipStream_t stream) {
    const float* x    = (const float*)d_in[0];
    const float* WQ   = (const float*)d_in[1];
    const float* bQ   = (const float*)d_in[2];
    const float* WK   = (const float*)d_in[3];
    const float* bK   = (const float*)d_in[4];
    const float* WV   = (const float*)d_in[5];
    const float* bV   = (const float*)d_in[6];
    const float* Wout = (const float*)d_in[7];
    const float* bout = (const float*)d_in[8];
    const float* Wori = (const float*)d_in[9];
    const float* bori = (const float*)d_in[10];
    float* out = (float*)d_out;

    char* ws = (char*)d_ws;
    u16* part = (u16*)ws;                              // 3*4*16*65536*2 = 25165824 B
    u16* qb = (u16*)(ws + 25165824);                   // 2 MB
    u16* kb = (u16*)(ws + 25165824 + 2097152);         // 2 MB
    u16* vT = (u16*)(ws + 25165824 + 2 * 2097152);     // 2 MB

    proj_partial<<<dim3(64, 3, 4), 256, 0, stream>>>(x, WQ, WK, WV, part);
    reduce_cast<<<dim3(32, 16, 3), 256, 0, stream>>>(part, bQ, bK, bV, qb, kb, vT);
    attn_kernel<<<dim3(32, 16), 256, 0, stream>>>(qb, kb, vT, Wout, bout, Wori, bori, out);
}